// Round 4
// baseline (262.227 us; speedup 1.0000x reference)
//
#include <hip/hip_runtime.h>

// One-pole IIR: out_t = b0*x_t + s_t ; s_{t+1} = a1c*s_t + k1*x_t,
// k1 = b1 + a1c*b0. |a1c| <= 0.5 -> 32-step halo truncation (~2^-32).
//
// v5: persistent waves + software pipeline (copy-kernel shape).
// v1-v4 (LDS / direct-LDS / barrier-free shuffle, occupancy 36-69%) ALL
// pinned at 79-85us / ~2.45 TB/s. Little's law: wave lifetime ~34K cyc vs
// ~1.5K critical path -> single-shot waves burst loads, drain, die, and
// re-launch serializes against drain. The 6.3 TB/s copy ubench is a
// persistent grid-stride loop with continuous issue; replicate that shape:
//  - 2048 blocks (8/CU), resident whole kernel; each wave runs 4 tiles.
//  - Two named tile sets A/B (static regs, no dynamic indexing), schedule
//    loadA,loadB, compA,loadA', compB,loadB', compA', compB' -> next tile's
//    5 loads always in flight under current tile's compute+stores; the
//    compiler's counted vmcnt never drains to 0 mid-wave.
// Math identical to v4: per-lane window sum W over its 16 floats,
// s_in(lane) = W_{l-1} + a^16 W_{l-2}; halo windows for lanes 0/1 from an
// 8-lane cooperative load of the previous 32 floats + 4-lane shfl reduce.

#define BLOCK 256
#define PER_LANE 16                       // floats per lane (one 64B line)
#define PER_WAVE (64 * PER_LANE)          // 1024
#define PER_BLOCK (BLOCK * PER_LANE)      // 4096
#define T_LEN 131072                      // PER_WAVE | T_LEN: no row straddle
#define ITERS 4                           // tiles per block

struct Coef {
    float b0, a, a2, a3, a4, a8, a12, a16, c0, c1, c2, c3;
};

struct Tile {
    float4 v0, v1, v2, v3, h;
    long long q0;                         // float4 index of lane's 4 quads
};

__device__ __forceinline__ void load_tile(Tile& T, const float4* __restrict__ xq,
                                          long long bt, int wid, int lane)
{
    const long long wb = bt * PER_BLOCK + (long long)wid * PER_WAVE;
    const long long wq = wb >> 2;
    T.q0 = wq + lane * 4;
    T.v0 = xq[T.q0 + 0];
    T.v1 = xq[T.q0 + 1];
    T.v2 = xq[T.q0 + 2];
    T.v3 = xq[T.q0 + 3];
    T.h  = make_float4(0.f, 0.f, 0.f, 0.f);
    const bool rs = ((wb & (long long)(T_LEN - 1)) == 0);
    if (lane < 8 && !rs)
        T.h = xq[wq - 8 + lane];          // [wb-32, wb), quad per lane
}

__device__ __forceinline__ void comp_store(const Tile& T, float4* __restrict__ oq,
                                           int lane, const Coef& C)
{
    // per-quad window partials: p = c3*x + c2*y + c1*z + c0*w
    const float pq0 = fmaf(C.c3, T.v0.x, fmaf(C.c2, T.v0.y, fmaf(C.c1, T.v0.z, C.c0 * T.v0.w)));
    const float pq1 = fmaf(C.c3, T.v1.x, fmaf(C.c2, T.v1.y, fmaf(C.c1, T.v1.z, C.c0 * T.v1.w)));
    const float pq2 = fmaf(C.c3, T.v2.x, fmaf(C.c2, T.v2.y, fmaf(C.c1, T.v2.z, C.c0 * T.v2.w)));
    const float pq3 = fmaf(C.c3, T.v3.x, fmaf(C.c2, T.v3.y, fmaf(C.c1, T.v3.z, C.c0 * T.v3.w)));
    const float W = fmaf(C.a4, fmaf(C.a4, fmaf(C.a4, pq0, pq1), pq2), pq3);

    // halo windows Wm1 ([-16,0)) and Wm2 ([-32,-16)) of this wave
    const float ph = fmaf(C.c3, T.h.x, fmaf(C.c2, T.h.y, fmaf(C.c1, T.h.z, C.c0 * T.h.w)));
    const int   r  = lane & 3;
    const float ws = (r == 0) ? C.a12 : (r == 1) ? C.a8 : (r == 2) ? C.a4 : 1.0f;
    float phs = ph * ws;                  // garbage on lanes >= 8 (never read)
    phs += __shfl_xor(phs, 1, 64);
    phs += __shfl_xor(phs, 2, 64);        // lanes 0-3 -> Wm2, lanes 4-7 -> Wm1
    const float Wm2 = __shfl(phs, 0, 64);
    const float Wm1 = __shfl(phs, 4, 64);

    // entering state: s = W_{l-1} + a^16 * W_{l-2}
    const float u1 = __shfl_up(W, 1, 64);
    const float u2 = __shfl_up(W, 2, 64);
    const float A_ = (lane >= 1) ? u1 : Wm1;
    const float B_ = (lane >= 2) ? u2 : ((lane == 1) ? Wm1 : Wm2);
    float s = fmaf(C.a16, B_, A_);

#define QUAD(V, PQ, IDX)                                                    \
    {                                                                       \
        const float4 v = (V);                                               \
        const float t1 = fmaf(C.c0, v.x, C.b0 * v.y);                       \
        const float t2 = fmaf(C.c1, v.x, fmaf(C.c0, v.y, C.b0 * v.z));      \
        const float t3 = fmaf(C.c2, v.x, fmaf(C.c1, v.y, fmaf(C.c0, v.z, C.b0 * v.w))); \
        float4 o;                                                           \
        o.x = fmaf(C.b0, v.x, s);                                           \
        o.y = fmaf(C.a,  s, t1);                                            \
        o.z = fmaf(C.a2, s, t2);                                            \
        o.w = fmaf(C.a3, s, t3);                                            \
        s = fmaf(C.a4, s, (PQ));                                            \
        oq[T.q0 + (IDX)] = o;                                               \
    }
    QUAD(T.v0, pq0, 0)
    QUAD(T.v1, pq1, 1)
    QUAD(T.v2, pq2, 2)
    QUAD(T.v3, pq3, 3)
#undef QUAD
}

__global__ __launch_bounds__(BLOCK, 8) void onepole_kernel(
    const float* __restrict__ x,
    const float* __restrict__ b0p,
    const float* __restrict__ b1p,
    const float* __restrict__ a1p,
    float* __restrict__ out)
{
    const int tid  = threadIdx.x;
    const int lane = tid & 63;
    const int wid  = tid >> 6;

    Coef C;
    C.b0 = b0p[0];
    const float b1 = b1p[0];
    float a = a1p[0];
    a = fminf(1.0f, fmaxf(-1.0f, a));
    C.a   = a;
    const float k1 = fmaf(a, C.b0, b1);
    C.a2  = a * a;   C.a3 = C.a2 * a;  C.a4 = C.a2 * C.a2;
    C.a8  = C.a4 * C.a4;  C.a12 = C.a8 * C.a4;  C.a16 = C.a8 * C.a8;
    C.c0  = k1;  C.c1 = k1 * a;  C.c2 = k1 * C.a2;  C.c3 = k1 * C.a3;

    const float4* xq = (const float4*)x;
    float4* oq = (float4*)out;

    const long long bt     = blockIdx.x;     // tile t: bt + t*stride
    const long long stride = gridDim.x;

    Tile A, B;
    load_tile(A, xq, bt + 0 * stride, wid, lane);
    load_tile(B, xq, bt + 1 * stride, wid, lane);
    comp_store(A, oq, lane, C);              // t0 (B in flight)
    load_tile(A, xq, bt + 2 * stride, wid, lane);
    comp_store(B, oq, lane, C);              // t1 (A' in flight)
    load_tile(B, xq, bt + 3 * stride, wid, lane);
    comp_store(A, oq, lane, C);              // t2 (B' in flight)
    comp_store(B, oq, lane, C);              // t3
}

extern "C" void kernel_launch(void* const* d_in, const int* in_sizes, int n_in,
                              void* d_out, int out_size, void* d_ws, size_t ws_size,
                              hipStream_t stream) {
    const float* x   = (const float*)d_in[0];
    const float* b0p = (const float*)d_in[1];
    const float* b1p = (const float*)d_in[2];
    const float* a1p = (const float*)d_in[3];
    float* outp = (float*)d_out;

    const int total   = in_sizes[0];            // B * T = 33554432 elements
    const int nblocks = total / PER_BLOCK;      // 8192 block-tiles
    const int grid    = nblocks / ITERS;        // 2048 persistent blocks

    onepole_kernel<<<grid, BLOCK, 0, stream>>>(x, b0p, b1p, a1p, outp);
}